// Round 5
// baseline (407.145 us; speedup 1.0000x reference)
//
#include <hip/hip_runtime.h>
#include <hip/hip_bf16.h>

// Problem constants
#define M_TOT   8192      // B*N tokens
#define D_IN    4096
#define D_OUT   4096
#define N_E     8
#define N_R     16
#define D_ATT   128
#define ER      128       // N_E*N_R
#define CATN    384       // 2*D_ATT + ER
#define KEXT    4224      // D_IN + ER (padded K for unified GEMM)
#define NTK     66        // KEXT/64 K-tiles (even)
#define NTM     32        // M_TOT/256

typedef __attribute__((ext_vector_type(8)))  __bf16 bf16x8;
typedef __attribute__((ext_vector_type(4)))  float  f32x4;
typedef __attribute__((ext_vector_type(16))) float  f32x16;

__device__ __forceinline__ ushort f2bf(float f) {
  union { float f; unsigned u; } v; v.f = f;
  unsigned r = (v.u + 0x7fffu + ((v.u >> 16) & 1u)) >> 16;
  return (ushort)r;
}

// ---- fp32 -> bf16, contiguous dest ----
__global__ void f2bf4_kernel(const float* __restrict__ in, ushort* __restrict__ out, long n4) {
  long i = blockIdx.x * (long)blockDim.x + threadIdx.x;
  if (i >= n4) return;
  const float4 a = reinterpret_cast<const float4*>(in)[i];
  ushort4 r; r.x = f2bf(a.x); r.y = f2bf(a.y); r.z = f2bf(a.z); r.w = f2bf(a.w);
  reinterpret_cast<ushort4*>(out)[i] = r;
}

// ---- fp32 [rows][4096] -> bf16 [rows][KEXT] (strided dest) ----
__global__ void f2bf4s_kernel(const float* __restrict__ in, ushort* __restrict__ out, long n4) {
  long i = blockIdx.x * (long)blockDim.x + threadIdx.x;
  if (i >= n4) return;
  const float4 a = reinterpret_cast<const float4*>(in)[i];
  ushort4 r; r.x = f2bf(a.x); r.y = f2bf(a.y); r.z = f2bf(a.z); r.w = f2bf(a.w);
  long row = i >> 10, c4 = (i & 1023) << 2;
  *reinterpret_cast<ushort4*>(out + row * KEXT + c4) = r;
}

// ---- Cat rows 256..383: Cat[256+j][d] = experts_A[e][d][r], j=e*16+r ----
__global__ void prep_catA_kernel(const float* __restrict__ expA, ushort* __restrict__ cat) {
  int idx = blockIdx.x * 256 + threadIdx.x;       // over 128*4096
  int j = idx >> 12, d = idx & 4095;
  int e = j >> 4, r = j & 15;
  cat[(size_t)(2 * D_ATT + j) * D_IN + d] = f2bf(expA[((size_t)e * D_IN + d) * N_R + r]);
}

// ---- w_ext cols 4096..4223: w_ext[o][4096+j] = experts_B_flat[j][o] ----
__global__ void prep_bt_kernel(const float* __restrict__ expB, ushort* __restrict__ we) {
  int idx = blockIdx.x * 256 + threadIdx.x;       // over 128*4096
  int j = idx >> 12, o = idx & 4095;              // coalesced read of expB row j
  we[(size_t)o * KEXT + D_IN + j] = f2bf(expB[(size_t)j * D_OUT + o]);
}

// ---- gating: P[m,0:128]=xV^T, P[m,128:256]=xU^T, P[m,256:384]=lora_down ----
// writes weighted lora-down into x_ext cols 4096..4223 (stride KEXT)
__global__ void gate_kernel(const float* __restrict__ P, const float* __restrict__ rW,
                            ushort* __restrict__ wtd) {
  int token = blockIdx.x * 4 + (threadIdx.x >> 6);
  int l = threadIdx.x & 63;
  const float* p = P + (size_t)token * CATN;
  float v0 = tanhf(p[l]);
  float v1 = tanhf(p[l + 64]);
  float u0 = 1.f / (1.f + __expf(-p[D_ATT + l]));
  float u1 = 1.f / (1.f + __expf(-p[D_ATT + l + 64]));
  float g0 = v0 * u0, g1 = v1 * u1;
  float rw[8];
  #pragma unroll
  for (int e = 0; e < 8; ++e) {
    float s = g0 * rW[e * D_ATT + l] + g1 * rW[e * D_ATT + l + 64];
    #pragma unroll
    for (int off = 32; off > 0; off >>= 1) s += __shfl_xor(s, off);
    rw[e] = 1.f / (1.f + __expf(-s));
  }
  int q = l >> 4;  // expert index within half (static-select to avoid scratch)
  float rw_a = (q == 0) ? rw[0] : (q == 1) ? rw[1] : (q == 2) ? rw[2] : rw[3];
  float rw_b = (q == 0) ? rw[4] : (q == 1) ? rw[5] : (q == 2) ? rw[6] : rw[7];
  wtd[(size_t)token * KEXT + l]      = f2bf(p[2 * D_ATT + l]      * rw_a);
  wtd[(size_t)token * KEXT + l + 64] = f2bf(p[2 * D_ATT + l + 64] * rw_b);
}

// ---- 128^2 m97-structure GEMM: P = x_ext[:, :4096] @ cat^T (compile-time dims) ----
__global__ __launch_bounds__(256, 2)
void gemm128_kernel(const ushort* __restrict__ A, const ushort* __restrict__ Bm,
                    float* __restrict__ C)
{
  __shared__ ushort As[128 * 64];
  __shared__ ushort Bs[128 * 64];
  const int tid = threadIdx.x;
  const int w = tid >> 6, l = tid & 63;
  const int wr = w >> 1, wc = w & 1;
  const int l16 = l & 15, lq = l >> 4;
  const int brow = blockIdx.y * 128;
  const int bcol = blockIdx.x * 128;

  f32x4 acc[4][4] = {};

  for (int kt = 0; kt < (D_IN >> 6); ++kt) {
    int k0 = kt << 6;
    #pragma unroll
    for (int c = 0; c < 4; ++c) {
      int rloc = w * 32 + c * 8;
      int rl = rloc + (l >> 3);
      int kk = k0 + (l & 7) * 8;
      const ushort* ga = A  + (size_t)(brow + rl) * KEXT + kk;
      const ushort* gb = Bm + (size_t)(bcol + rl) * D_IN + kk;
      __builtin_amdgcn_global_load_lds((const __attribute__((address_space(1))) void*)ga,
                                       (__attribute__((address_space(3))) void*)(As + rloc * 64),
                                       16, 0, 0);
      __builtin_amdgcn_global_load_lds((const __attribute__((address_space(1))) void*)gb,
                                       (__attribute__((address_space(3))) void*)(Bs + rloc * 64),
                                       16, 0, 0);
    }
    __syncthreads();

    #pragma unroll
    for (int ks = 0; ks < 2; ++ks) {
      bf16x8 af[4], bfv[4];
      #pragma unroll
      for (int mi = 0; mi < 4; ++mi)
        af[mi] = *reinterpret_cast<const bf16x8*>(As + (wr * 64 + mi * 16 + l16) * 64 + ks * 32 + lq * 8);
      #pragma unroll
      for (int ni = 0; ni < 4; ++ni)
        bfv[ni] = *reinterpret_cast<const bf16x8*>(Bs + (wc * 64 + ni * 16 + l16) * 64 + ks * 32 + lq * 8);
      #pragma unroll
      for (int mi = 0; mi < 4; ++mi)
        #pragma unroll
        for (int ni = 0; ni < 4; ++ni)
          acc[mi][ni] = __builtin_amdgcn_mfma_f32_16x16x32_bf16(af[mi], bfv[ni], acc[mi][ni], 0, 0, 0);
    }
    __syncthreads();
  }

  #pragma unroll
  for (int ni = 0; ni < 4; ++ni) {
    int col = bcol + wc * 64 + ni * 16 + l16;
    #pragma unroll
    for (int mi = 0; mi < 4; ++mi) {
      f32x4 v = acc[mi][ni];
      int row0 = brow + wr * 64 + mi * 16 + lq * 4;
      #pragma unroll
      for (int j = 0; j < 4; ++j)
        C[(size_t)(row0 + j) * CATN + col] = v[j];
    }
  }
}

// ---- 256^2 8-phase GEMM, 32x32x16 MFMA core: out = x_ext @ w_ext^T + bias ----
// 8 waves (2M x 4N); wave tile 128x64 = 4 mtiles x 2 ntiles of 32x32.
// BK=64 (4 K-slices of 16), double-buffered LDS (128 KiB), full 3-bit swizzle.
// Same proven barrier/STAGE/vmcnt schedule as the 16x16 version (R4); only the
// fragment geometry and MFMA shape changed (2495 vs 2176 TF pipe ceiling, m119).
// A-frag (32x32x16): lane l -> row = l&31, k = (l>>5)*8 + [0..7]; B symmetric.
// C/D: col = l&31, row = (reg&3) + 8*(reg>>2) + 4*(l>>5)  [m74/m101-verified].
__global__ __launch_bounds__(512, 2)
void gemm256_kernel(const ushort* __restrict__ A, const ushort* __restrict__ Bm,
                    float* __restrict__ C, const float* __restrict__ bias)
{
  __shared__ ushort lds[2][2][2][8192];   // [buf][mat 0=A 1=B][half][128*64]
  const int tid = threadIdx.x;
  const int wid = tid >> 6, l = tid & 63;
  const int wr = wid >> 2, wc = wid & 3;
  const int l31 = l & 31, hi8 = (l >> 5) * 8;
  const int rxor = (l & 7) << 3;               // read-side elem XOR (row&7)<<3

  // XCD-aware 2D chunking: 512 blocks = 8 XCDs x 64; each XCD gets an 8x8
  // block chunk (A refetched 2x, B 4x -> ~276 MB ideal vs 553 MB N-major).
  const int xcd = (int)blockIdx.x & 7, q = (int)blockIdx.x >> 3;
  const int brow = ((xcd >> 1) * 8 + (q >> 3)) * 256;
  const int bcol = ((xcd & 1) * 8 + (q & 7)) * 256;

  // staging: linear LDS dest; global source col pre-swizzled by dest row&7
  const int srow = tid >> 3;
  const int scol = (((tid & 7) ^ ((tid >> 3) & 7)) << 3);

#define STAGE(buf_, mat_, half_, kt_) do {                                        \
    const ushort* _s = (mat_) ? Bm : A;                                           \
    int _rb = ((mat_) ? bcol : brow) + (half_) * 128 + srow;                      \
    ushort* _d = &lds[(buf_)][(mat_)][(half_)][wid * 512];                        \
    _Pragma("unroll")                                                             \
    for (int _c = 0; _c < 2; ++_c) {                                              \
      const ushort* _g = _s + (size_t)(_rb + _c * 64) * KEXT + (kt_) * 64 + scol; \
      __builtin_amdgcn_global_load_lds(                                           \
          (const __attribute__((address_space(1))) void*)_g,                      \
          (__attribute__((address_space(3))) void*)(_d + _c * 4096), 16, 0, 0);   \
    } } while (0)

#define LDA32(buf_, mt_, ks_) \
  (*reinterpret_cast<const bf16x8*>(&lds[(buf_)][0][wr][((mt_) * 32 + l31) * 64 + ((((ks_) * 16) + hi8) ^ rxor)]))
#define LDB32(buf_, nt_, ks_) \
  (*reinterpret_cast<const bf16x8*>(&lds[(buf_)][1][wc >> 1][((wc & 1) * 64 + (nt_) * 32 + l31) * 64 + ((((ks_) * 16) + hi8) ^ rxor)]))

#define RD32_A(buf_, mb_, dst_) \
    _Pragma("unroll") for (int mt = 0; mt < 2; ++mt) \
      _Pragma("unroll") for (int ks = 0; ks < 4; ++ks) dst_[mt][ks] = LDA32(buf_, (mb_) + mt, ks);
#define RD32_B(buf_, nt_, dst_) \
    _Pragma("unroll") for (int ks = 0; ks < 4; ++ks) dst_[ks] = LDB32(buf_, nt_, ks);

#define MFMA_Q32(mb_, n_, a_, b_) \
    _Pragma("unroll") for (int ks = 0; ks < 4; ++ks) \
      _Pragma("unroll") for (int mt = 0; mt < 2; ++mt) \
        acc[(mb_) + mt][n_] = __builtin_amdgcn_mfma_f32_32x32x16_bf16( \
            a_[mt][ks], b_[ks], acc[(mb_) + mt][n_], 0, 0, 0);

#define TILE(t_, buf_, aIn_, b0In_, aOut_, b0Out_) do {                           \
    bf16x8 b1[4], aHi[2][4];                                                      \
    const int ktA = ((t_) + 1 < NTK) ? (t_) + 1 : NTK - 1;                        \
    const int ktB = ((t_) + 2 < NTK) ? (t_) + 2 : NTK - 1;                        \
    /* P1: rd B-hi | MFMA AloxBlo */                                              \
    STAGE(buf_ ^ 1, 0, 0, ktA);                                                   \
    __builtin_amdgcn_s_barrier();                                                 \
    asm volatile("s_waitcnt lgkmcnt(0)" ::: "memory");                            \
    __builtin_amdgcn_s_setprio(1);                                                \
    RD32_B(buf_, 1, b1);                                                          \
    MFMA_Q32(0, 0, aIn_, b0In_);                                                  \
    __builtin_amdgcn_s_setprio(0);                                                \
    __builtin_amdgcn_s_barrier();                                                 \
    /* P2: rd A-hi | MFMA AloxBhi */                                              \
    STAGE(buf_ ^ 1, 0, 1, ktA);                                                   \
    __builtin_amdgcn_s_barrier();                                                 \
    asm volatile("s_waitcnt lgkmcnt(0)" ::: "memory");                            \
    __builtin_amdgcn_s_setprio(1);                                                \
    RD32_A(buf_, 2, aHi);                                                         \
    MFMA_Q32(0, 1, aIn_, b1);                                                     \
    __builtin_amdgcn_s_setprio(0);                                                \
    __builtin_amdgcn_s_barrier();                                                 \
    /* P3: MFMA AhixBhi */                                                        \
    STAGE(buf_, 1, 0, ktB);                                                       \
    __builtin_amdgcn_s_barrier();                                                 \
    asm volatile("s_waitcnt lgkmcnt(0)" ::: "memory");                            \
    __builtin_amdgcn_s_setprio(1);                                                \
    MFMA_Q32(2, 1, aHi, b1);                                                      \
    __builtin_amdgcn_s_setprio(0);                                                \
    __builtin_amdgcn_s_barrier();                                                 \
    /* P4: rd next Alo+Blo | MFMA AhixBlo */                                      \
    STAGE(buf_, 1, 1, ktB);                                                       \
    asm volatile("s_waitcnt vmcnt(4)" ::: "memory");                              \
    __builtin_amdgcn_s_barrier();                                                 \
    __builtin_amdgcn_s_setprio(1);                                                \
    RD32_A(buf_ ^ 1, 0, aOut_);                                                   \
    RD32_B(buf_ ^ 1, 0, b0Out_);                                                  \
    MFMA_Q32(2, 0, aHi, b0In_);                                                   \
    __builtin_amdgcn_s_setprio(0);                                                \
    __builtin_amdgcn_s_barrier();                                                 \
  } while (0)

  f32x16 acc[4][2] = {};
  bf16x8 aA[2][4], b0A[4], aB[2][4], b0B[4];

  // prologue: tile 0 complete + B(1); leave B(1) in flight, then pre-read R1(0)
  STAGE(0, 0, 0, 0); STAGE(0, 0, 1, 0);
  STAGE(0, 1, 0, 0); STAGE(0, 1, 1, 0);
  STAGE(1, 1, 0, 1); STAGE(1, 1, 1, 1);
  asm volatile("s_waitcnt vmcnt(4)" ::: "memory");
  __builtin_amdgcn_s_barrier();
  RD32_A(0, 0, aA);
  RD32_B(0, 0, b0A);

  #pragma unroll 1
  for (int tp = 0; tp < NTK / 2; ++tp) {
    TILE(2 * tp,     0, aA, b0A, aB, b0B);
    TILE(2 * tp + 1, 1, aB, b0B, aA, b0A);
  }

  asm volatile("s_waitcnt vmcnt(0) lgkmcnt(0)" ::: "memory");

  // epilogue: C/D 32x32 layout col=l&31, row=(reg&3)+8*(reg>>2)+4*(l>>5)
  #pragma unroll
  for (int nt = 0; nt < 2; ++nt) {
    int col = bcol + wc * 64 + nt * 32 + l31;
    float bs = bias[col];
    #pragma unroll
    for (int mt = 0; mt < 4; ++mt) {
      f32x16 v = acc[mt][nt];
      int row0 = brow + wr * 128 + mt * 32 + 4 * (l >> 5);
      #pragma unroll
      for (int reg = 0; reg < 16; ++reg) {
        int row = row0 + (reg & 3) + 8 * (reg >> 2);
        C[(size_t)row * D_OUT + col] = v[reg] + bs;
      }
    }
  }
#undef STAGE
#undef LDA32
#undef LDB32
#undef RD32_A
#undef RD32_B
#undef MFMA_Q32
#undef TILE
}

extern "C" void kernel_launch(void* const* d_in, const int* in_sizes, int n_in,
                              void* d_out, int out_size, void* d_ws, size_t ws_size,
                              hipStream_t stream) {
  const float* x      = (const float*)d_in[0];
  const float* weight = (const float*)d_in[1];
  const float* bias   = (const float*)d_in[2];
  const float* rV     = (const float*)d_in[3];
  const float* rU     = (const float*)d_in[4];
  const float* rW     = (const float*)d_in[5];
  const float* expA   = (const float*)d_in[6];
  const float* expB   = (const float*)d_in[7];
  float* out = (float*)d_out;

  // workspace: x_ext[8192][4224], w_ext[4096][4224], cat[384][4096], P[8192][384]
  ushort* xe  = (ushort*)d_ws;
  ushort* we  = xe  + (size_t)M_TOT * KEXT;
  ushort* cat = we  + (size_t)D_OUT * KEXT;
  float*  P   = (float*)(cat + (size_t)CATN * D_IN);

  long n4;
  n4 = (long)M_TOT * D_IN / 4;
  f2bf4s_kernel<<<dim3((n4 + 255) / 256), 256, 0, stream>>>(x, xe, n4);
  n4 = (long)D_OUT * D_IN / 4;
  f2bf4s_kernel<<<dim3((n4 + 255) / 256), 256, 0, stream>>>(weight, we, n4);
  n4 = (long)D_ATT * D_IN / 4;
  f2bf4_kernel<<<dim3((n4 + 255) / 256), 256, 0, stream>>>(rV, cat, n4);
  f2bf4_kernel<<<dim3((n4 + 255) / 256), 256, 0, stream>>>(rU, cat + (size_t)D_ATT * D_IN, n4);
  prep_catA_kernel<<<dim3(ER * D_IN / 256), 256, 0, stream>>>(expA, cat);
  prep_bt_kernel<<<dim3(ER * D_OUT / 256), 256, 0, stream>>>(expB, we);

  // P = x @ Cat^T   [8192, 384]
  gemm128_kernel<<<dim3(CATN / 128, M_TOT / 128), 256, 0, stream>>>(xe, cat, P);

  // weighted lora-down -> x_ext cols 4096..4223
  gate_kernel<<<dim3(M_TOT / 4), 256, 0, stream>>>(P, rW, xe + D_IN);

  // out = x_ext @ w_ext^T + bias   [8192, 4096], K = 4224
  gemm256_kernel<<<dim3((D_OUT / 256) * (M_TOT / 256)), 512, 0, stream>>>(xe, we, out, bias);
}

// Round 6
// 354.774 us; speedup vs baseline: 1.1476x; 1.1476x over previous
//
#include <hip/hip_runtime.h>
#include <hip/hip_bf16.h>

// Problem constants
#define M_TOT   8192      // B*N tokens
#define D_IN    4096
#define D_OUT   4096
#define N_E     8
#define N_R     16
#define D_ATT   128
#define ER      128       // N_E*N_R
#define CATN    384       // 2*D_ATT + ER
#define KEXT    4224      // D_IN + ER (padded K for unified GEMM)
#define NTK     66        // KEXT/64 K-tiles (even)

typedef __attribute__((ext_vector_type(8)))  __bf16 bf16x8;
typedef __attribute__((ext_vector_type(4)))  float  f32x4;

__device__ __forceinline__ ushort f2bf(float f) {
  union { float f; unsigned u; } v; v.f = f;
  unsigned r = (v.u + 0x7fffu + ((v.u >> 16) & 1u)) >> 16;
  return (ushort)r;
}
__device__ __forceinline__ float bf2f(ushort u) {
  union { unsigned u; float f; } v; v.u = ((unsigned)u) << 16;
  return v.f;
}

// ---- fp32 -> bf16, contiguous dest ----
__global__ void f2bf4_kernel(const float* __restrict__ in, ushort* __restrict__ out, long n4) {
  long i = blockIdx.x * (long)blockDim.x + threadIdx.x;
  if (i >= n4) return;
  const float4 a = reinterpret_cast<const float4*>(in)[i];
  ushort4 r; r.x = f2bf(a.x); r.y = f2bf(a.y); r.z = f2bf(a.z); r.w = f2bf(a.w);
  reinterpret_cast<ushort4*>(out)[i] = r;
}

// ---- fp32 [rows][4096] -> bf16 [rows][KEXT] (strided dest) ----
__global__ void f2bf4s_kernel(const float* __restrict__ in, ushort* __restrict__ out, long n4) {
  long i = blockIdx.x * (long)blockDim.x + threadIdx.x;
  if (i >= n4) return;
  const float4 a = reinterpret_cast<const float4*>(in)[i];
  ushort4 r; r.x = f2bf(a.x); r.y = f2bf(a.y); r.z = f2bf(a.z); r.w = f2bf(a.w);
  long row = i >> 10, c4 = (i & 1023) << 2;
  *reinterpret_cast<ushort4*>(out + row * KEXT + c4) = r;
}

// ---- Cat rows 256..383: Cat[256+j][d] = experts_A[e][d][r], j=e*16+r ----
__global__ void prep_catA_kernel(const float* __restrict__ expA, ushort* __restrict__ cat) {
  int idx = blockIdx.x * 256 + threadIdx.x;       // over 128*4096
  int j = idx >> 12, d = idx & 4095;
  int e = j >> 4, r = j & 15;
  cat[(size_t)(2 * D_ATT + j) * D_IN + d] = f2bf(expA[((size_t)e * D_IN + d) * N_R + r]);
}

// ---- w_ext cols 4096..4223: w_ext[o][4096+j] = experts_B_flat[j][o] ----
__global__ void prep_bt_kernel(const float* __restrict__ expB, ushort* __restrict__ we) {
  int idx = blockIdx.x * 256 + threadIdx.x;       // over 128*4096
  int j = idx >> 12, o = idx & 4095;              // coalesced read of expB row j
  we[(size_t)o * KEXT + D_IN + j] = f2bf(expB[(size_t)j * D_OUT + o]);
}

// ---- gating over split-K partials P[2][M][CATN] (bf16):
// P[*][m,0:128]=xV^T, [128:256]=xU^T, [256:384]=lora_down; writes weighted
// lora-down into x_ext cols 4096..4223 (stride KEXT)
__global__ void gate_kernel(const ushort* __restrict__ P, const float* __restrict__ rW,
                            ushort* __restrict__ wtd) {
  int token = blockIdx.x * 4 + (threadIdx.x >> 6);
  int l = threadIdx.x & 63;
  const ushort* p0 = P + (size_t)token * CATN;
  const ushort* p1 = p0 + (size_t)M_TOT * CATN;
  float v0 = tanhf(bf2f(p0[l])      + bf2f(p1[l]));
  float v1 = tanhf(bf2f(p0[l + 64]) + bf2f(p1[l + 64]));
  float u0 = 1.f / (1.f + __expf(-(bf2f(p0[D_ATT + l])      + bf2f(p1[D_ATT + l]))));
  float u1 = 1.f / (1.f + __expf(-(bf2f(p0[D_ATT + l + 64]) + bf2f(p1[D_ATT + l + 64]))));
  float g0 = v0 * u0, g1 = v1 * u1;
  float rw[8];
  #pragma unroll
  for (int e = 0; e < 8; ++e) {
    float s = g0 * rW[e * D_ATT + l] + g1 * rW[e * D_ATT + l + 64];
    #pragma unroll
    for (int off = 32; off > 0; off >>= 1) s += __shfl_xor(s, off);
    rw[e] = 1.f / (1.f + __expf(-s));
  }
  int q = l >> 4;  // expert index within half (static-select to avoid scratch)
  float rw_a = (q == 0) ? rw[0] : (q == 1) ? rw[1] : (q == 2) ? rw[2] : rw[3];
  float rw_b = (q == 0) ? rw[4] : (q == 1) ? rw[5] : (q == 2) ? rw[6] : rw[7];
  float lo_a = bf2f(p0[2 * D_ATT + l])      + bf2f(p1[2 * D_ATT + l]);
  float lo_b = bf2f(p0[2 * D_ATT + l + 64]) + bf2f(p1[2 * D_ATT + l + 64]);
  wtd[(size_t)token * KEXT + l]      = f2bf(lo_a * rw_a);
  wtd[(size_t)token * KEXT + l + 64] = f2bf(lo_b * rw_b);
}

// ---- 128^2 m97-structure router GEMM, split-K=2 (blockIdx.z): ----
// P[z] = x_ext[:, z*2048:(z+1)*2048] @ cat[:, same]^T  (bf16 partials)
__global__ __launch_bounds__(256, 2)
void gemm128_kernel(const ushort* __restrict__ A, const ushort* __restrict__ Bm,
                    ushort* __restrict__ C)
{
  __shared__ ushort As[128 * 64];
  __shared__ ushort Bs[128 * 64];
  const int tid = threadIdx.x;
  const int w = tid >> 6, l = tid & 63;
  const int wr = w >> 1, wc = w & 1;
  const int l16 = l & 15, lq = l >> 4;
  const int brow = blockIdx.y * 128;
  const int bcol = blockIdx.x * 128;
  const int kt0 = (int)blockIdx.z << 5;           // 32 K-tiles per split

  f32x4 acc[4][4] = {};

  for (int kt = kt0; kt < kt0 + 32; ++kt) {
    int k0 = kt << 6;
    #pragma unroll
    for (int c = 0; c < 4; ++c) {
      int rloc = w * 32 + c * 8;
      int rl = rloc + (l >> 3);
      int kk = k0 + (l & 7) * 8;
      const ushort* ga = A  + (size_t)(brow + rl) * KEXT + kk;
      const ushort* gb = Bm + (size_t)(bcol + rl) * D_IN + kk;
      __builtin_amdgcn_global_load_lds((const __attribute__((address_space(1))) void*)ga,
                                       (__attribute__((address_space(3))) void*)(As + rloc * 64),
                                       16, 0, 0);
      __builtin_amdgcn_global_load_lds((const __attribute__((address_space(1))) void*)gb,
                                       (__attribute__((address_space(3))) void*)(Bs + rloc * 64),
                                       16, 0, 0);
    }
    __syncthreads();

    #pragma unroll
    for (int ks = 0; ks < 2; ++ks) {
      bf16x8 af[4], bfv[4];
      #pragma unroll
      for (int mi = 0; mi < 4; ++mi)
        af[mi] = *reinterpret_cast<const bf16x8*>(As + (wr * 64 + mi * 16 + l16) * 64 + ks * 32 + lq * 8);
      #pragma unroll
      for (int ni = 0; ni < 4; ++ni)
        bfv[ni] = *reinterpret_cast<const bf16x8*>(Bs + (wc * 64 + ni * 16 + l16) * 64 + ks * 32 + lq * 8);
      #pragma unroll
      for (int mi = 0; mi < 4; ++mi)
        #pragma unroll
        for (int ni = 0; ni < 4; ++ni)
          acc[mi][ni] = __builtin_amdgcn_mfma_f32_16x16x32_bf16(af[mi], bfv[ni], acc[mi][ni], 0, 0, 0);
    }
    __syncthreads();
  }

  ushort* Cz = C + (size_t)blockIdx.z * M_TOT * CATN;
  #pragma unroll
  for (int ni = 0; ni < 4; ++ni) {
    int col = bcol + wc * 64 + ni * 16 + l16;
    #pragma unroll
    for (int mi = 0; mi < 4; ++mi) {
      f32x4 v = acc[mi][ni];
      int row0 = brow + wr * 64 + mi * 16 + lq * 4;
      #pragma unroll
      for (int j = 0; j < 4; ++j)
        Cz[(size_t)(row0 + j) * CATN + col] = f2bf(v[j]);
    }
  }
}

// ---- 256^2 8-phase GEMM with READ ROTATION (R4-proven 16x16 core) ----
// + 2D XCD chunking (R5-proven: FETCH 557->205 MB).
// 8 waves (2M x 4N), BK=64, double-buffered LDS (128 KiB), full 3-bit swizzle
// (elem' = elem ^ ((row&7)<<3); linear LDS dest + inverse-swizzled global src).
// Per tile t (buf=t&1):
//  P1: stage Ah0(t+1); bar; lgkm0[waits R1 from prev P4]; {rd B-hi | MFMA AloxBlo}; bar
//  P2: stage Ah1(t+1); bar; lgkm0[waits B-hi];           {rd A-hi | MFMA AloxBhi}; bar
//  P3: stage Bh0(t+2); bar; lgkm0[waits A-hi];           {        MFMA AhixBhi}; bar
//  P4: stage Bh1(t+2); vmcnt(4); bar;                    {rd R1(t+1) | MFMA AhixBlo}; bar
__global__ __launch_bounds__(512, 2)
void gemm256_kernel(const ushort* __restrict__ A, const ushort* __restrict__ Bm,
                    float* __restrict__ C, const float* __restrict__ bias)
{
  __shared__ ushort lds[2][2][2][8192];   // [buf][mat 0=A 1=B][half][128*64]
  const int tid = threadIdx.x;
  const int wid = tid >> 6, l = tid & 63;
  const int wr = wid >> 2, wc = wid & 3;
  const int l16 = l & 15, lq = l >> 4;
  const int rxor = (l16 & 7) << 3;             // read-side elem XOR (row&7)<<3

  // XCD-aware 2D chunking: 512 blocks = 8 XCDs x 64; each XCD an 8x8 chunk.
  const int xcd = (int)blockIdx.x & 7, q = (int)blockIdx.x >> 3;
  const int brow = ((xcd >> 1) * 8 + (q >> 3)) * 256;
  const int bcol = ((xcd & 1) * 8 + (q & 7)) * 256;

  // staging: linear LDS dest; global source col pre-swizzled by dest row&7
  const int srow = tid >> 3;
  const int scol = (((tid & 7) ^ ((tid >> 3) & 7)) << 3);

#define STAGE(buf_, mat_, half_, kt_) do {                                        \
    const ushort* _s = (mat_) ? Bm : A;                                           \
    int _rb = ((mat_) ? bcol : brow) + (half_) * 128 + srow;                      \
    ushort* _d = &lds[(buf_)][(mat_)][(half_)][wid * 512];                        \
    _Pragma("unroll")                                                             \
    for (int _c = 0; _c < 2; ++_c) {                                              \
      const ushort* _g = _s + (size_t)(_rb + _c * 64) * KEXT + (kt_) * 64 + scol; \
      __builtin_amdgcn_global_load_lds(                                           \
          (const __attribute__((address_space(1))) void*)_g,                      \
          (__attribute__((address_space(3))) void*)(_d + _c * 4096), 16, 0, 0);   \
    } } while (0)

#define LDA_FRAG(buf_, mi_, ks_) \
  (*reinterpret_cast<const bf16x8*>(&lds[(buf_)][0][wr][((mi_) * 16 + l16) * 64 + (((ks_) * 32 + lq * 8) ^ rxor)]))
#define LDB_FRAG(buf_, ni_, ks_) \
  (*reinterpret_cast<const bf16x8*>(&lds[(buf_)][1][wc >> 1][((wc & 1) * 64 + (ni_) * 16 + l16) * 64 + (((ks_) * 32 + lq * 8) ^ rxor)]))

#define RD_ALO(buf_, dst_) \
    _Pragma("unroll") for (int mi = 0; mi < 4; ++mi) \
      _Pragma("unroll") for (int ks = 0; ks < 2; ++ks) dst_[mi][ks] = LDA_FRAG(buf_, mi, ks);
#define RD_BLO(buf_, dst_) \
    _Pragma("unroll") for (int ni = 0; ni < 2; ++ni) \
      _Pragma("unroll") for (int ks = 0; ks < 2; ++ks) dst_[ni][ks] = LDB_FRAG(buf_, ni, ks);

#define MFMA_Q(accm0_, accn0_, a_, b_) \
    _Pragma("unroll") for (int mi = 0; mi < 4; ++mi) \
      _Pragma("unroll") for (int ni = 0; ni < 2; ++ni) \
        _Pragma("unroll") for (int ks = 0; ks < 2; ++ks) \
          acc[(accm0_) + mi][(accn0_) + ni] = __builtin_amdgcn_mfma_f32_16x16x32_bf16( \
              a_[mi][ks], b_[ni][ks], acc[(accm0_) + mi][(accn0_) + ni], 0, 0, 0);

#define TILE(t_, buf_, aIn_, b0In_, aOut_, b0Out_) do {                           \
    bf16x8 b1[2][2], aHi[4][2];                                                   \
    const int ktA = ((t_) + 1 < NTK) ? (t_) + 1 : NTK - 1;                        \
    const int ktB = ((t_) + 2 < NTK) ? (t_) + 2 : NTK - 1;                        \
    /* P1 */                                                                      \
    STAGE(buf_ ^ 1, 0, 0, ktA);                                                   \
    __builtin_amdgcn_s_barrier();                                                 \
    asm volatile("s_waitcnt lgkmcnt(0)" ::: "memory");                            \
    __builtin_amdgcn_s_setprio(1);                                                \
    _Pragma("unroll") for (int ni = 0; ni < 2; ++ni)                              \
      _Pragma("unroll") for (int ks = 0; ks < 2; ++ks)                            \
        b1[ni][ks] = LDB_FRAG(buf_, ni + 2, ks);                                  \
    MFMA_Q(0, 0, aIn_, b0In_);                                                    \
    __builtin_amdgcn_s_setprio(0);                                                \
    __builtin_amdgcn_s_barrier();                                                 \
    /* P2 */                                                                      \
    STAGE(buf_ ^ 1, 0, 1, ktA);                                                   \
    __builtin_amdgcn_s_barrier();                                                 \
    asm volatile("s_waitcnt lgkmcnt(0)" ::: "memory");                            \
    __builtin_amdgcn_s_setprio(1);                                                \
    _Pragma("unroll") for (int mi = 0; mi < 4; ++mi)                              \
      _Pragma("unroll") for (int ks = 0; ks < 2; ++ks)                            \
        aHi[mi][ks] = LDA_FRAG(buf_, mi + 4, ks);                                 \
    MFMA_Q(0, 2, aIn_, b1);                                                       \
    __builtin_amdgcn_s_setprio(0);                                                \
    __builtin_amdgcn_s_barrier();                                                 \
    /* P3 */                                                                      \
    STAGE(buf_, 1, 0, ktB);                                                       \
    __builtin_amdgcn_s_barrier();                                                 \
    asm volatile("s_waitcnt lgkmcnt(0)" ::: "memory");                            \
    __builtin_amdgcn_s_setprio(1);                                                \
    MFMA_Q(4, 2, aHi, b1);                                                        \
    __builtin_amdgcn_s_setprio(0);                                                \
    __builtin_amdgcn_s_barrier();                                                 \
    /* P4 */                                                                      \
    STAGE(buf_, 1, 1, ktB);                                                       \
    asm volatile("s_waitcnt vmcnt(4)" ::: "memory");                              \
    __builtin_amdgcn_s_barrier();                                                 \
    __builtin_amdgcn_s_setprio(1);                                                \
    RD_ALO(buf_ ^ 1, aOut_);                                                      \
    RD_BLO(buf_ ^ 1, b0Out_);                                                     \
    MFMA_Q(4, 0, aHi, b0In_);                                                     \
    __builtin_amdgcn_s_setprio(0);                                                \
    __builtin_amdgcn_s_barrier();                                                 \
  } while (0)

  f32x4 acc[8][4] = {};
  bf16x8 aA[4][2], b0A[2][2], aB[4][2], b0B[2][2];

  // prologue: tile 0 complete + B(1); leave B(1) in flight, then pre-read R1(0)
  STAGE(0, 0, 0, 0); STAGE(0, 0, 1, 0);
  STAGE(0, 1, 0, 0); STAGE(0, 1, 1, 0);
  STAGE(1, 1, 0, 1); STAGE(1, 1, 1, 1);
  asm volatile("s_waitcnt vmcnt(4)" ::: "memory");
  __builtin_amdgcn_s_barrier();
  RD_ALO(0, aA);
  RD_BLO(0, b0A);

  #pragma unroll 1
  for (int tp = 0; tp < NTK / 2; ++tp) {
    TILE(2 * tp,     0, aA, b0A, aB, b0B);
    TILE(2 * tp + 1, 1, aB, b0B, aA, b0A);
  }

  asm volatile("s_waitcnt vmcnt(0) lgkmcnt(0)" ::: "memory");

  // epilogue: C/D layout col=l&15, row=(l>>4)*4+j (m89-verified)
  #pragma unroll
  for (int ni = 0; ni < 4; ++ni) {
    int col = bcol + wc * 64 + ni * 16 + l16;
    float bs = bias[col];
    #pragma unroll
    for (int mi = 0; mi < 8; ++mi) {
      int row0 = brow + wr * 128 + mi * 16 + lq * 4;
      #pragma unroll
      for (int j = 0; j < 4; ++j)
        C[(size_t)(row0 + j) * D_OUT + col] = acc[mi][ni][j] + bs;
    }
  }
#undef STAGE
#undef LDA_FRAG
#undef LDB_FRAG
#undef RD_ALO
#undef RD_BLO
#undef MFMA_Q
#undef TILE
}

extern "C" void kernel_launch(void* const* d_in, const int* in_sizes, int n_in,
                              void* d_out, int out_size, void* d_ws, size_t ws_size,
                              hipStream_t stream) {
  const float* x      = (const float*)d_in[0];
  const float* weight = (const float*)d_in[1];
  const float* bias   = (const float*)d_in[2];
  const float* rV     = (const float*)d_in[3];
  const float* rU     = (const float*)d_in[4];
  const float* rW     = (const float*)d_in[5];
  const float* expA   = (const float*)d_in[6];
  const float* expB   = (const float*)d_in[7];
  float* out = (float*)d_out;

  // workspace: x_ext[8192][4224], w_ext[4096][4224], cat[384][4096],
  // P[2][8192][384] bf16 split-K partials  (total ~119.5 MB, same as R2-R5)
  ushort* xe  = (ushort*)d_ws;
  ushort* we  = xe  + (size_t)M_TOT * KEXT;
  ushort* cat = we  + (size_t)D_OUT * KEXT;
  ushort* P   = cat + (size_t)CATN * D_IN;

  long n4;
  n4 = (long)M_TOT * D_IN / 4;
  f2bf4s_kernel<<<dim3((n4 + 255) / 256), 256, 0, stream>>>(x, xe, n4);
  n4 = (long)D_OUT * D_IN / 4;
  f2bf4s_kernel<<<dim3((n4 + 255) / 256), 256, 0, stream>>>(weight, we, n4);
  n4 = (long)D_ATT * D_IN / 4;
  f2bf4_kernel<<<dim3((n4 + 255) / 256), 256, 0, stream>>>(rV, cat, n4);
  f2bf4_kernel<<<dim3((n4 + 255) / 256), 256, 0, stream>>>(rU, cat + (size_t)D_ATT * D_IN, n4);
  prep_catA_kernel<<<dim3(ER * D_IN / 256), 256, 0, stream>>>(expA, cat);
  prep_bt_kernel<<<dim3(ER * D_OUT / 256), 256, 0, stream>>>(expB, we);

  // P[z] = x @ Cat^T partials   [2][8192, 384], split-K=2
  gemm128_kernel<<<dim3(CATN / 128, M_TOT / 128, 2), 256, 0, stream>>>(xe, cat, P);

  // weighted lora-down -> x_ext cols 4096..4223
  gate_kernel<<<dim3(M_TOT / 4), 256, 0, stream>>>(P, rW, xe + D_IN);

  // out = x_ext @ w_ext^T + bias   [8192, 4096], K = 4224
  gemm256_kernel<<<dim3((D_OUT / 256) * (M_TOT / 256)), 512, 0, stream>>>(xe, we, out, bias);
}

// Round 7
// 341.056 us; speedup vs baseline: 1.1938x; 1.0402x over previous
//
#include <hip/hip_runtime.h>
#include <hip/hip_bf16.h>

// Problem constants
#define M_TOT   8192      // B*N tokens
#define D_IN    4096
#define D_OUT   4096
#define N_E     8
#define N_R     16
#define D_ATT   128
#define ER      128       // N_E*N_R
#define CATN    384       // 2*D_ATT + ER
#define KEXT    4224      // D_IN + ER (padded K for unified GEMM)
#define NTK     66        // KEXT/64 K-tiles (even)
#define NX4     (8388608L)  // M_TOT*D_IN/4
#define NW4     (4194304L)  // D_OUT*D_IN/4

typedef __attribute__((ext_vector_type(8)))  __bf16 bf16x8;
typedef __attribute__((ext_vector_type(4)))  float  f32x4;

__device__ __forceinline__ ushort f2bf(float f) {
  union { float f; unsigned u; } v; v.f = f;
  unsigned r = (v.u + 0x7fffu + ((v.u >> 16) & 1u)) >> 16;
  return (ushort)r;
}
__device__ __forceinline__ float bf2f(ushort u) {
  union { unsigned u; float f; } v; v.u = ((unsigned)u) << 16;
  return v.f;
}

// ---- merged fp32->bf16 conversion of x and weight into strided [*][KEXT] ----
__global__ void conv_xw_kernel(const float* __restrict__ x, const float* __restrict__ w,
                               ushort* __restrict__ xe, ushort* __restrict__ we) {
  long i = blockIdx.x * (long)blockDim.x + threadIdx.x;  // grid exact: NX4+NW4
  const float* src; ushort* dst; long j;
  if (i < NX4) { src = x; dst = xe; j = i; }
  else         { src = w; dst = we; j = i - NX4; }
  const float4 a = reinterpret_cast<const float4*>(src)[j];
  ushort4 r; r.x = f2bf(a.x); r.y = f2bf(a.y); r.z = f2bf(a.z); r.w = f2bf(a.w);
  long row = j >> 10, c4 = (j & 1023) << 2;
  *reinterpret_cast<ushort4*>(dst + row * KEXT + c4) = r;
}

// ---- merged small preps: rV/rU -> cat rows 0..255 (float4 conv),
// expA -> cat rows 256..383 (Cat[256+e*16+r][d] = expA[e][d][r]),
// expB -> we cols 4096.. (we[o][4096+j] = expB[j][o]).  5120 blocks total.
__global__ void prep_small_kernel(const float* __restrict__ rV, const float* __restrict__ rU,
                                  const float* __restrict__ expA, const float* __restrict__ expB,
                                  ushort* __restrict__ cat, ushort* __restrict__ we) {
  int b = blockIdx.x;
  if (b < 1024) {                       // rV (512) + rU (512), float4 elems
    const float* src = (b < 512) ? rV : rU;
    ushort* dst = cat + ((b < 512) ? 0 : (size_t)D_ATT * D_IN);
    int i = (b & 511) * 256 + threadIdx.x;          // < 131072
    const float4 a = reinterpret_cast<const float4*>(src)[i];
    ushort4 r; r.x = f2bf(a.x); r.y = f2bf(a.y); r.z = f2bf(a.z); r.w = f2bf(a.w);
    reinterpret_cast<ushort4*>(dst)[i] = r;
  } else if (b < 3072) {                // catA scatter
    int idx = (b - 1024) * 256 + threadIdx.x;       // < 524288
    int j = idx >> 12, d = idx & 4095;
    int e = j >> 4, r = j & 15;
    cat[(size_t)(2 * D_ATT + j) * D_IN + d] = f2bf(expA[((size_t)e * D_IN + d) * N_R + r]);
  } else {                              // bt transpose
    int idx = (b - 3072) * 256 + threadIdx.x;       // < 524288
    int j = idx >> 12, o = idx & 4095;              // coalesced read of expB row j
    we[(size_t)o * KEXT + D_IN + j] = f2bf(expB[(size_t)j * D_OUT + o]);
  }
}

// ---- gating over split-K partials P[2][M][CATN] (bf16):
// P[*][m,0:128]=xV^T, [128:256]=xU^T, [256:384]=lora_down; writes weighted
// lora-down into x_ext cols 4096..4223 (stride KEXT)
__global__ void gate_kernel(const ushort* __restrict__ P, const float* __restrict__ rW,
                            ushort* __restrict__ wtd) {
  int token = blockIdx.x * 4 + (threadIdx.x >> 6);
  int l = threadIdx.x & 63;
  const ushort* p0 = P + (size_t)token * CATN;
  const ushort* p1 = p0 + (size_t)M_TOT * CATN;
  float v0 = tanhf(bf2f(p0[l])      + bf2f(p1[l]));
  float v1 = tanhf(bf2f(p0[l + 64]) + bf2f(p1[l + 64]));
  float u0 = 1.f / (1.f + __expf(-(bf2f(p0[D_ATT + l])      + bf2f(p1[D_ATT + l]))));
  float u1 = 1.f / (1.f + __expf(-(bf2f(p0[D_ATT + l + 64]) + bf2f(p1[D_ATT + l + 64]))));
  float g0 = v0 * u0, g1 = v1 * u1;
  float rw[8];
  #pragma unroll
  for (int e = 0; e < 8; ++e) {
    float s = g0 * rW[e * D_ATT + l] + g1 * rW[e * D_ATT + l + 64];
    #pragma unroll
    for (int off = 32; off > 0; off >>= 1) s += __shfl_xor(s, off);
    rw[e] = 1.f / (1.f + __expf(-s));
  }
  int q = l >> 4;  // expert index within half (static-select to avoid scratch)
  float rw_a = (q == 0) ? rw[0] : (q == 1) ? rw[1] : (q == 2) ? rw[2] : rw[3];
  float rw_b = (q == 0) ? rw[4] : (q == 1) ? rw[5] : (q == 2) ? rw[6] : rw[7];
  float lo_a = bf2f(p0[2 * D_ATT + l])      + bf2f(p1[2 * D_ATT + l]);
  float lo_b = bf2f(p0[2 * D_ATT + l + 64]) + bf2f(p1[2 * D_ATT + l + 64]);
  wtd[(size_t)token * KEXT + l]      = f2bf(lo_a * rw_a);
  wtd[(size_t)token * KEXT + l + 64] = f2bf(lo_b * rw_b);
}

// ---- 128^2 m97-structure router GEMM, split-K=2 (blockIdx.z): ----
// P[z] = x_ext[:, z*2048:(z+1)*2048] @ cat[:, same]^T  (bf16 partials)
// launch_bounds(256,4): 4 blocks/CU co-resident (LDS 4x32KB=128<=160, VGPR 60)
// -- the 2-barrier m97 structure relies on multi-block TLP (m114).
__global__ __launch_bounds__(256, 4)
void gemm128_kernel(const ushort* __restrict__ A, const ushort* __restrict__ Bm,
                    ushort* __restrict__ C)
{
  __shared__ ushort As[128 * 64];
  __shared__ ushort Bs[128 * 64];
  const int tid = threadIdx.x;
  const int w = tid >> 6, l = tid & 63;
  const int wr = w >> 1, wc = w & 1;
  const int l16 = l & 15, lq = l >> 4;
  const int brow = blockIdx.y * 128;
  const int bcol = blockIdx.x * 128;
  const int kt0 = (int)blockIdx.z << 5;           // 32 K-tiles per split

  f32x4 acc[4][4] = {};

  for (int kt = kt0; kt < kt0 + 32; ++kt) {
    int k0 = kt << 6;
    #pragma unroll
    for (int c = 0; c < 4; ++c) {
      int rloc = w * 32 + c * 8;
      int rl = rloc + (l >> 3);
      int kk = k0 + (l & 7) * 8;
      const ushort* ga = A  + (size_t)(brow + rl) * KEXT + kk;
      const ushort* gb = Bm + (size_t)(bcol + rl) * D_IN + kk;
      __builtin_amdgcn_global_load_lds((const __attribute__((address_space(1))) void*)ga,
                                       (__attribute__((address_space(3))) void*)(As + rloc * 64),
                                       16, 0, 0);
      __builtin_amdgcn_global_load_lds((const __attribute__((address_space(1))) void*)gb,
                                       (__attribute__((address_space(3))) void*)(Bs + rloc * 64),
                                       16, 0, 0);
    }
    __syncthreads();

    #pragma unroll
    for (int ks = 0; ks < 2; ++ks) {
      bf16x8 af[4], bfv[4];
      #pragma unroll
      for (int mi = 0; mi < 4; ++mi)
        af[mi] = *reinterpret_cast<const bf16x8*>(As + (wr * 64 + mi * 16 + l16) * 64 + ks * 32 + lq * 8);
      #pragma unroll
      for (int ni = 0; ni < 4; ++ni)
        bfv[ni] = *reinterpret_cast<const bf16x8*>(Bs + (wc * 64 + ni * 16 + l16) * 64 + ks * 32 + lq * 8);
      #pragma unroll
      for (int mi = 0; mi < 4; ++mi)
        #pragma unroll
        for (int ni = 0; ni < 4; ++ni)
          acc[mi][ni] = __builtin_amdgcn_mfma_f32_16x16x32_bf16(af[mi], bfv[ni], acc[mi][ni], 0, 0, 0);
    }
    __syncthreads();
  }

  ushort* Cz = C + (size_t)blockIdx.z * M_TOT * CATN;
  #pragma unroll
  for (int ni = 0; ni < 4; ++ni) {
    int col = bcol + wc * 64 + ni * 16 + l16;
    #pragma unroll
    for (int mi = 0; mi < 4; ++mi) {
      f32x4 v = acc[mi][ni];
      int row0 = brow + wr * 64 + mi * 16 + lq * 4;
      #pragma unroll
      for (int j = 0; j < 4; ++j)
        Cz[(size_t)(row0 + j) * CATN + col] = f2bf(v[j]);
    }
  }
}

// ---- 256^2 8-phase GEMM with READ ROTATION (R4-proven 16x16 core) ----
// + 2D XCD chunking (R5-proven: FETCH 557->205 MB).
// 8 waves (2M x 4N), BK=64, double-buffered LDS (128 KiB), full 3-bit swizzle
// (elem' = elem ^ ((row&7)<<3); linear LDS dest + inverse-swizzled global src).
// Per tile t (buf=t&1):
//  P1: stage Ah0(t+1); bar; lgkm0[waits R1 from prev P4]; {rd B-hi | MFMA AloxBlo}; bar
//  P2: stage Ah1(t+1); bar; lgkm0[waits B-hi];           {rd A-hi | MFMA AloxBhi}; bar
//  P3: stage Bh0(t+2); bar; lgkm0[waits A-hi];           {        MFMA AhixBhi}; bar
//  P4: stage Bh1(t+2); vmcnt(4); bar;                    {rd R1(t+1) | MFMA AhixBlo}; bar
__global__ __launch_bounds__(512, 2)
void gemm256_kernel(const ushort* __restrict__ A, const ushort* __restrict__ Bm,
                    float* __restrict__ C, const float* __restrict__ bias)
{
  __shared__ ushort lds[2][2][2][8192];   // [buf][mat 0=A 1=B][half][128*64]
  const int tid = threadIdx.x;
  const int wid = tid >> 6, l = tid & 63;
  const int wr = wid >> 2, wc = wid & 3;
  const int l16 = l & 15, lq = l >> 4;
  const int rxor = (l16 & 7) << 3;             // read-side elem XOR (row&7)<<3

  // XCD-aware 2D chunking: 512 blocks = 8 XCDs x 64; each XCD an 8x8 chunk.
  const int xcd = (int)blockIdx.x & 7, q = (int)blockIdx.x >> 3;
  const int brow = ((xcd >> 1) * 8 + (q >> 3)) * 256;
  const int bcol = ((xcd & 1) * 8 + (q & 7)) * 256;

  // staging: linear LDS dest; global source col pre-swizzled by dest row&7
  const int srow = tid >> 3;
  const int scol = (((tid & 7) ^ ((tid >> 3) & 7)) << 3);

#define STAGE(buf_, mat_, half_, kt_) do {                                        \
    const ushort* _s = (mat_) ? Bm : A;                                           \
    int _rb = ((mat_) ? bcol : brow) + (half_) * 128 + srow;                      \
    ushort* _d = &lds[(buf_)][(mat_)][(half_)][wid * 512];                        \
    _Pragma("unroll")                                                             \
    for (int _c = 0; _c < 2; ++_c) {                                              \
      const ushort* _g = _s + (size_t)(_rb + _c * 64) * KEXT + (kt_) * 64 + scol; \
      __builtin_amdgcn_global_load_lds(                                           \
          (const __attribute__((address_space(1))) void*)_g,                      \
          (__attribute__((address_space(3))) void*)(_d + _c * 4096), 16, 0, 0);   \
    } } while (0)

#define LDA_FRAG(buf_, mi_, ks_) \
  (*reinterpret_cast<const bf16x8*>(&lds[(buf_)][0][wr][((mi_) * 16 + l16) * 64 + (((ks_) * 32 + lq * 8) ^ rxor)]))
#define LDB_FRAG(buf_, ni_, ks_) \
  (*reinterpret_cast<const bf16x8*>(&lds[(buf_)][1][wc >> 1][((wc & 1) * 64 + (ni_) * 16 + l16) * 64 + (((ks_) * 32 + lq * 8) ^ rxor)]))

#define RD_ALO(buf_, dst_) \
    _Pragma("unroll") for (int mi = 0; mi < 4; ++mi) \
      _Pragma("unroll") for (int ks = 0; ks < 2; ++ks) dst_[mi][ks] = LDA_FRAG(buf_, mi, ks);
#define RD_BLO(buf_, dst_) \
    _Pragma("unroll") for (int ni = 0; ni < 2; ++ni) \
      _Pragma("unroll") for (int ks = 0; ks < 2; ++ks) dst_[ni][ks] = LDB_FRAG(buf_, ni, ks);

#define MFMA_Q(accm0_, accn0_, a_, b_) \
    _Pragma("unroll") for (int mi = 0; mi < 4; ++mi) \
      _Pragma("unroll") for (int ni = 0; ni < 2; ++ni) \
        _Pragma("unroll") for (int ks = 0; ks < 2; ++ks) \
          acc[(accm0_) + mi][(accn0_) + ni] = __builtin_amdgcn_mfma_f32_16x16x32_bf16( \
              a_[mi][ks], b_[ni][ks], acc[(accm0_) + mi][(accn0_) + ni], 0, 0, 0);

#define TILE(t_, buf_, aIn_, b0In_, aOut_, b0Out_) do {                           \
    bf16x8 b1[2][2], aHi[4][2];                                                   \
    const int ktA = ((t_) + 1 < NTK) ? (t_) + 1 : NTK - 1;                        \
    const int ktB = ((t_) + 2 < NTK) ? (t_) + 2 : NTK - 1;                        \
    /* P1 */                                                                      \
    STAGE(buf_ ^ 1, 0, 0, ktA);                                                   \
    __builtin_amdgcn_s_barrier();                                                 \
    asm volatile("s_waitcnt lgkmcnt(0)" ::: "memory");                            \
    __builtin_amdgcn_s_setprio(1);                                                \
    _Pragma("unroll") for (int ni = 0; ni < 2; ++ni)                              \
      _Pragma("unroll") for (int ks = 0; ks < 2; ++ks)                            \
        b1[ni][ks] = LDB_FRAG(buf_, ni + 2, ks);                                  \
    MFMA_Q(0, 0, aIn_, b0In_);                                                    \
    __builtin_amdgcn_s_setprio(0);                                                \
    __builtin_amdgcn_s_barrier();                                                 \
    /* P2 */                                                                      \
    STAGE(buf_ ^ 1, 0, 1, ktA);                                                   \
    __builtin_amdgcn_s_barrier();                                                 \
    asm volatile("s_waitcnt lgkmcnt(0)" ::: "memory");                            \
    __builtin_amdgcn_s_setprio(1);                                                \
    _Pragma("unroll") for (int mi = 0; mi < 4; ++mi)                              \
      _Pragma("unroll") for (int ks = 0; ks < 2; ++ks)                            \
        aHi[mi][ks] = LDA_FRAG(buf_, mi + 4, ks);                                 \
    MFMA_Q(0, 2, aIn_, b1);                                                       \
    __builtin_amdgcn_s_setprio(0);                                                \
    __builtin_amdgcn_s_barrier();                                                 \
    /* P3 */                                                                      \
    STAGE(buf_, 1, 0, ktB);                                                       \
    __builtin_amdgcn_s_barrier();                                                 \
    asm volatile("s_waitcnt lgkmcnt(0)" ::: "memory");                            \
    __builtin_amdgcn_s_setprio(1);                                                \
    MFMA_Q(4, 2, aHi, b1);                                                        \
    __builtin_amdgcn_s_setprio(0);                                                \
    __builtin_amdgcn_s_barrier();                                                 \
    /* P4 */                                                                      \
    STAGE(buf_, 1, 1, ktB);                                                       \
    asm volatile("s_waitcnt vmcnt(4)" ::: "memory");                              \
    __builtin_amdgcn_s_barrier();                                                 \
    __builtin_amdgcn_s_setprio(1);                                                \
    RD_ALO(buf_ ^ 1, aOut_);                                                      \
    RD_BLO(buf_ ^ 1, b0Out_);                                                     \
    MFMA_Q(4, 0, aHi, b0In_);                                                     \
    __builtin_amdgcn_s_setprio(0);                                                \
    __builtin_amdgcn_s_barrier();                                                 \
  } while (0)

  f32x4 acc[8][4] = {};
  bf16x8 aA[4][2], b0A[2][2], aB[4][2], b0B[2][2];

  // prologue: tile 0 complete + B(1); leave B(1) in flight, then pre-read R1(0)
  STAGE(0, 0, 0, 0); STAGE(0, 0, 1, 0);
  STAGE(0, 1, 0, 0); STAGE(0, 1, 1, 0);
  STAGE(1, 1, 0, 1); STAGE(1, 1, 1, 1);
  asm volatile("s_waitcnt vmcnt(4)" ::: "memory");
  __builtin_amdgcn_s_barrier();
  RD_ALO(0, aA);
  RD_BLO(0, b0A);

  #pragma unroll 1
  for (int tp = 0; tp < NTK / 2; ++tp) {
    TILE(2 * tp,     0, aA, b0A, aB, b0B);
    TILE(2 * tp + 1, 1, aB, b0B, aA, b0A);
  }

  asm volatile("s_waitcnt vmcnt(0) lgkmcnt(0)" ::: "memory");

  // epilogue: C/D layout col=l&15, row=(l>>4)*4+j (m89-verified)
  #pragma unroll
  for (int ni = 0; ni < 4; ++ni) {
    int col = bcol + wc * 64 + ni * 16 + l16;
    float bs = bias[col];
    #pragma unroll
    for (int mi = 0; mi < 8; ++mi) {
      int row0 = brow + wr * 128 + mi * 16 + lq * 4;
      #pragma unroll
      for (int j = 0; j < 4; ++j)
        C[(size_t)(row0 + j) * D_OUT + col] = acc[mi][ni][j] + bs;
    }
  }
#undef STAGE
#undef LDA_FRAG
#undef LDB_FRAG
#undef RD_ALO
#undef RD_BLO
#undef MFMA_Q
#undef TILE
}

extern "C" void kernel_launch(void* const* d_in, const int* in_sizes, int n_in,
                              void* d_out, int out_size, void* d_ws, size_t ws_size,
                              hipStream_t stream) {
  const float* x      = (const float*)d_in[0];
  const float* weight = (const float*)d_in[1];
  const float* bias   = (const float*)d_in[2];
  const float* rV     = (const float*)d_in[3];
  const float* rU     = (const float*)d_in[4];
  const float* rW     = (const float*)d_in[5];
  const float* expA   = (const float*)d_in[6];
  const float* expB   = (const float*)d_in[7];
  float* out = (float*)d_out;

  // workspace: x_ext[8192][4224], w_ext[4096][4224], cat[384][4096],
  // P[2][8192][384] bf16 split-K partials  (total ~119.5 MB, same as R2-R6)
  ushort* xe  = (ushort*)d_ws;
  ushort* we  = xe  + (size_t)M_TOT * KEXT;
  ushort* cat = we  + (size_t)D_OUT * KEXT;
  ushort* P   = cat + (size_t)CATN * D_IN;

  // x + weight -> bf16 strided  (one launch, grid exact)
  conv_xw_kernel<<<dim3((NX4 + NW4) / 256), 256, 0, stream>>>(x, weight, xe, we);

  // rV/rU/expA/expB preps (one launch)
  prep_small_kernel<<<dim3(5120), 256, 0, stream>>>(rV, rU, expA, expB, cat, we);

  // P[z] = x @ Cat^T partials   [2][8192, 384], split-K=2
  gemm128_kernel<<<dim3(CATN / 128, M_TOT / 128, 2), 256, 0, stream>>>(xe, cat, P);

  // weighted lora-down -> x_ext cols 4096..4223
  gate_kernel<<<dim3(M_TOT / 4), 256, 0, stream>>>(P, rW, xe + D_IN);

  // out = x_ext @ w_ext^T + bias   [8192, 4096], K = 4224
  gemm256_kernel<<<dim3((D_OUT / 256) * (M_TOT / 256)), 512, 0, stream>>>(xe, we, out, bias);
}